// Round 8
// baseline (156.510 us; speedup 1.0000x reference)
//
#include <hip/hip_runtime.h>
#include <hip/hip_bf16.h>

#define N 8192
#define D 128
#define T64 64
#define NT64 (N / T64)   // 128 tile-rows; NPAIR = 128*129/2 = 8256 = 64*3 + 4032*2
#define GRID_KB 1024     // 4096 waves

typedef __attribute__((ext_vector_type(4))) int intx4;
typedef unsigned long long u64;
typedef unsigned int u32;

static __device__ inline float softplus_of(const float* __restrict__ phi) {
    float p = phi[0];
    return (p > 20.f) ? p : log1pf(__expf(p));
}

// ---- workspace layout (within d_ws) ----
// ctrl[0] = done-counter (zeroed by kA), ctrl[1] = sqmin (u32 atomicMin; the
// harness's 0xAA poison = 2.86e9 acts as +inf since real sqv < 2.1e6)
// rowsum: N floats @ +256 B; sqv: N ints; q8: N*D int8

// kA: q8[r,k] = int8(rint(16*x[r,k])); sqv[r] = ||q_r||^2 (exact int);
// rowsum zero; ctrl[1] = min_r sqv via u32 atomicMin; ctrl[0] = 0.
__global__ __launch_bounds__(256) void kA_prep(
        const float* __restrict__ x, signed char* __restrict__ q8,
        int* __restrict__ sqv, float* __restrict__ rowsum,
        u32* __restrict__ ctrl) {
    int gid = blockIdx.x * 256 + threadIdx.x;
    int row = gid >> 4;
    int gc  = gid & 15;

    const float* xs = x + (size_t)row * D + gc * 8;
    float4 u = *(const float4*)xs, v = *(const float4*)(xs + 4);
    float f[8] = {u.x, u.y, u.z, u.w, v.x, v.y, v.z, v.w};
    u64 pack = 0;
    int s = 0;
    #pragma unroll
    for (int k = 0; k < 8; k++) {
        float c = fminf(fmaxf(f[k] * 16.f, -127.f), 127.f);
        int q = (int)rintf(c);
        s += q * q;
        pack |= ((u64)(q & 255)) << (8 * k);
    }
    *(u64*)&q8[(size_t)row * D + gc * 8] = pack;

    #pragma unroll
    for (int m = 1; m < 16; m <<= 1) s += __shfl_xor(s, m, 64);
    if (gc == 0) { sqv[row] = s; rowsum[row] = 0.f; }

    u32 ms = (u32)s;
    ms = min(ms, (u32)__shfl_xor((int)ms, 16, 64));
    ms = min(ms, (u32)__shfl_xor((int)ms, 32, 64));
    if ((threadIdx.x & 63) == 0) atomicMin(&ctrl[1], ms);
    if (gid == 0) ctrl[0] = 0;
}

// kB: fused out-write + screened symmetric int8 Gram + last-block finalize.
// Per 64x64 tile-pair: 32 MFMA, then an O(1)-per-element screen:
//   prune iff 2*max(acc) <= 2*sqmin_all - Ts   (=> all d2s >= Ts, each
//   pruned term < 2^-30; total IXT error < 1e-5). Flagged nt-columns
//   (128 diagonal tiles + ~hundreds of near pairs) take the exact exp2
//   slow path (gathers + atomics live only there). Barrier-free K-loop,
//   no LDS; 1024 blocks, 4096 waves, 2 pairs each (3 for w<64).
__global__ __launch_bounds__(256, 3) void kB_gram(
        const float* __restrict__ x, const float* __restrict__ phi,
        const float* __restrict__ noise, float* __restrict__ out,
        const signed char* __restrict__ q8, const int* __restrict__ sqv,
        float* __restrict__ rowsum, u32* __restrict__ ctrl) {
    const int tid  = threadIdx.x;
    const int w    = blockIdx.x * 4 + (tid >> 6);
    const int lane = tid & 63;
    const int lrow = lane & 15;
    const int quad = lane >> 4;

    // ---- out = x + var*noise: issue loads now, finish after the pair loop ----
    const int og = blockIdx.x * 256 + tid;          // 1024*256 = N*D/4 exactly
    float4 xv = ((const float4*)x)[og];
    float4 nv = ((const float4*)noise)[og];

    float var = softplus_of(phi);
    const float c2 = ((-0.5f / var) * 1.4426950408889634f) * (1.f / 256.f);
    const int  Ts = (int)ceilf(30.f / (-c2));
    const int  thr2 = 2 * (int)ctrl[1] - Ts;        // prune iff 2*accmax <= thr2

    const int cnt = (w < 64) ? 3 : 2;
    int start     = (w < 64) ? 3 * w : 2 * w + 64;
    int ti = 0, rem = start, len = NT64;
    while (rem >= len) { rem -= len; ++ti; --len; }
    int tj = ti + rem;

    intx4 af[4][2], bf[4][2];
    int curTi = -1;

    #pragma unroll
    for (int nt = 0; nt < 4; nt++) {
        const signed char* br = q8 + (size_t)(tj * T64 + nt * 16 + lrow) * D + quad * 16;
        bf[nt][0] = *(const intx4*)br;
        bf[nt][1] = *(const intx4*)(br + 64);
    }

    for (int r = 0; r < cnt; ++r) {
        const int iB = ti * T64, jB = tj * T64;

        if (ti != curTi) {
            #pragma unroll
            for (int mt = 0; mt < 4; mt++) {
                const signed char* ar = q8 + (size_t)(iB + mt * 16 + lrow) * D + quad * 16;
                af[mt][0] = *(const intx4*)ar;
                af[mt][1] = *(const intx4*)(ar + 64);
            }
            curTi = ti;
        }

        int nti = ti, ntj = tj + 1;
        if (ntj == NT64) { ++nti; ntj = nti; }
        const bool more = (r + 1 < cnt);

        #pragma unroll
        for (int nt = 0; nt < 4; nt++) {
            intx4 acc[4] = {};
            #pragma unroll
            for (int kk = 0; kk < 2; kk++)
                #pragma unroll
                for (int mt = 0; mt < 4; mt++)
                    acc[mt] = __builtin_amdgcn_mfma_i32_16x16x64_i8(
                        af[mt][kk], bf[nt][kk], acc[mt], 0, 0, 0);

            if (more) {  // prefetch next pair's bf[nt]; never drained by a barrier
                const signed char* br =
                    q8 + (size_t)(ntj * T64 + nt * 16 + lrow) * D + quad * 16;
                bf[nt][0] = *(const intx4*)br;
                bf[nt][1] = *(const intx4*)(br + 64);
            }

            // ---- O(1)/elem screen: lane-local max, then __any ----
            int lm = acc[0][0];
            #pragma unroll
            for (int mt = 0; mt < 4; mt++)
                #pragma unroll
                for (int reg = 0; reg < 4; reg++)
                    lm = max(lm, acc[mt][reg]);

            if (__any(2 * lm > thr2)) {
                // exact slow path (diag tiles + rare near pairs)
                // C/D layout: col = lane&15, row = quad*4 + reg [learn_hip m89]
                const int sj = sqv[jB + nt * 16 + lrow];
                float colv = 0.f;
                #pragma unroll
                for (int mt = 0; mt < 4; mt++)
                    #pragma unroll
                    for (int reg = 0; reg < 4; reg++) {
                        int si = sqv[iB + mt * 16 + quad * 4 + reg];
                        int d2s = si + sj - (acc[mt][reg] << 1);
                        float p = __builtin_amdgcn_exp2f((float)d2s * c2);
                        colv += p;
                        float rv = p;
                        rv += __shfl_xor(rv, 1, 64);
                        rv += __shfl_xor(rv, 2, 64);
                        rv += __shfl_xor(rv, 4, 64);
                        rv += __shfl_xor(rv, 8, 64);
                        if (lrow == 0)
                            atomicAdd(&rowsum[iB + mt * 16 + quad * 4 + reg], rv);
                    }
                if (ti != tj) {  // symmetric column contribution
                    colv += __shfl_xor(colv, 16, 64);
                    colv += __shfl_xor(colv, 32, 64);
                    if (quad == 0)
                        atomicAdd(&rowsum[jB + nt * 16 + lrow], colv);
                }
            }
        }

        ti = nti; tj = ntj;
    }

    // ---- finish the out-write (loads long complete) ----
    float4 ov;
    ov.x = xv.x + var * nv.x; ov.y = xv.y + var * nv.y;
    ov.z = xv.z + var * nv.z; ov.w = xv.w + var * nv.w;
    ((float4*)out)[og] = ov;

    // ---- last-block-done finalize (replaces k3: one fewer dispatch) ----
    __shared__ int amLast;
    __shared__ float red[4];
    __syncthreads();
    if (tid == 0) {
        __threadfence();
        amLast = (atomicAdd(&ctrl[0], 1u) == GRID_KB - 1);
    }
    __syncthreads();
    if (amLast) {
        __threadfence();
        float local = 0.f;
        for (int i = tid; i < N; i += 256) local += logf(rowsum[i]);
        #pragma unroll
        for (int m = 1; m < 64; m <<= 1) local += __shfl_xor(local, m, 64);
        if ((tid & 63) == 0) red[tid >> 6] = local;
        __syncthreads();
        if (tid == 0) {
            float kde = (red[0] + red[1] + red[2] + red[3]) / (float)N;
            out[(size_t)N * D] = (logf((float)N) - kde) * 1.4426950408889634f;
        }
    }
}

extern "C" void kernel_launch(void* const* d_in, const int* in_sizes, int n_in,
                              void* d_out, int out_size, void* d_ws, size_t ws_size,
                              hipStream_t stream) {
    const float* x     = (const float*)d_in[0];
    const float* phi   = (const float*)d_in[1];
    const float* noise = (const float*)d_in[2];
    float* out = (float*)d_out;

    u32*   ctrl   = (u32*)d_ws;                          // [0]=done, [1]=sqmin
    float* rowsum = (float*)((char*)d_ws + 256);         // N floats
    int*   sqv    = (int*)(rowsum + N);                  // N ints
    signed char* q8 = (signed char*)(sqv + N);           // N*D int8 = 1 MB

    kA_prep<<<(N * 16) / 256, 256, 0, stream>>>(x, q8, sqv, rowsum, ctrl);
    kB_gram<<<GRID_KB, 256, 0, stream>>>(x, phi, noise, out, q8, sqv, rowsum, ctrl);
}

// Round 9
// 117.172 us; speedup vs baseline: 1.3357x; 1.3357x over previous
//
#include <hip/hip_runtime.h>
#include <hip/hip_bf16.h>

#define N 8192
#define D 128
#define T64 64
#define NT64 (N / T64)   // 128 tile-rows; NPAIR = 128*129/2 = 8256 = 64*3 + 4032*2

typedef __attribute__((ext_vector_type(4))) int intx4;
typedef unsigned long long u64;
typedef unsigned int u32;

static __device__ inline float softplus_of(const float* __restrict__ phi) {
    float p = phi[0];
    return (p > 20.f) ? p : log1pf(__expf(p));
}

// k1: out = x + var*noise; q8[r,k] = int8(rint(16*x[r,k])); sqv[r] = ||q_r||^2
// (exact int); sqtmin[t] = min over tile t's 64 rows (u32 atomicMin against
// the harness's 0xAA poison = 2.86e9, which acts as +inf since real sq < 2.1e6
// — if ws ever arrived zeroed instead, the screen degrades to all-slow-path,
// which is slow but still exact); rowsum zero-init.
__global__ __launch_bounds__(256) void k1_prep(
        const float* __restrict__ x, const float* __restrict__ phi,
        const float* __restrict__ noise, float* __restrict__ out,
        signed char* __restrict__ q8, int* __restrict__ sqv,
        u32* __restrict__ sqtmin, float* __restrict__ rowsum) {
    int gid = blockIdx.x * 256 + threadIdx.x;
    int row = gid >> 4;
    int gc  = gid & 15;
    float var = softplus_of(phi);

    const float* xs = x     + (size_t)row * D + gc * 8;
    const float* ns = noise + (size_t)row * D + gc * 8;
    float4 u  = *(const float4*)xs, v  = *(const float4*)(xs + 4);
    float4 nu = *(const float4*)ns, nv = *(const float4*)(ns + 4);

    float4 o0, o1;
    o0.x = u.x + var * nu.x; o0.y = u.y + var * nu.y;
    o0.z = u.z + var * nu.z; o0.w = u.w + var * nu.w;
    o1.x = v.x + var * nv.x; o1.y = v.y + var * nv.y;
    o1.z = v.z + var * nv.z; o1.w = v.w + var * nv.w;
    float* od = out + (size_t)row * D + gc * 8;
    *(float4*)od = o0; *(float4*)(od + 4) = o1;

    float f[8] = {u.x, u.y, u.z, u.w, v.x, v.y, v.z, v.w};
    u64 pack = 0;
    int s = 0;
    #pragma unroll
    for (int k = 0; k < 8; k++) {
        float c = fminf(fmaxf(f[k] * 16.f, -127.f), 127.f);
        int q = (int)rintf(c);
        s += q * q;
        pack |= ((u64)(q & 255)) << (8 * k);
    }
    *(u64*)&q8[(size_t)row * D + gc * 8] = pack;

    #pragma unroll
    for (int m = 1; m < 16; m <<= 1) s += __shfl_xor(s, m, 64);  // row sum
    if (gc == 0) { sqv[row] = s; rowsum[row] = 0.f; }

    u32 ms = (u32)s;                                  // min over wave's 4 rows
    ms = min(ms, (u32)__shfl_xor((int)ms, 16, 64));
    ms = min(ms, (u32)__shfl_xor((int)ms, 32, 64));
    if ((threadIdx.x & 63) == 0) atomicMin(&sqtmin[row >> 6], ms);
}

// k2: screened symmetric int8 Gram. 1024 blocks (4/CU, one round), 4096
// waves, 2 pairs each (3 for w<64). Per 64x64 pair: 8 B-loads + 32 MFMA +
// per-nt O(1) screen: prune iff 2*max(acc) <= sqtmin[ti]+sqtmin[tj]-Ts
// (=> every exact d2s >= Ts, each pruned term < 2^-30, IXT error < 1e-5).
// Per-tile mins put the prune margin at ~6 sigma -> slow path is exactly
// the 128 diagonal tiles. Barrier-free, no LDS, no fences.
__global__ __launch_bounds__(256, 4) void k2_gram(
        const signed char* __restrict__ q8, const float* __restrict__ phi,
        const int* __restrict__ sqv, const u32* __restrict__ sqtmin,
        float* __restrict__ rowsum) {
    const int tid  = threadIdx.x;
    const int w    = blockIdx.x * 4 + (tid >> 6);
    const int lane = tid & 63;
    const int lrow = lane & 15;
    const int quad = lane >> 4;

    const int cnt = (w < 64) ? 3 : 2;
    int start     = (w < 64) ? 3 * w : 2 * w + 64;
    int ti = 0, rem = start, len = NT64;
    while (rem >= len) { rem -= len; ++ti; --len; }
    int tj = ti + rem;

    float var = softplus_of(phi);
    const float c2 = ((-0.5f / var) * 1.4426950408889634f) * (1.f / 256.f);
    const int  Ts = (int)ceilf(30.f / (-c2));

    intx4 af[4][2], bf[4][2];
    int curTi = -1;

    #pragma unroll
    for (int nt = 0; nt < 4; nt++) {
        const signed char* br = q8 + (size_t)(tj * T64 + nt * 16 + lrow) * D + quad * 16;
        bf[nt][0] = *(const intx4*)br;
        bf[nt][1] = *(const intx4*)(br + 64);
    }

    for (int r = 0; r < cnt; ++r) {
        const int iB = ti * T64, jB = tj * T64;
        const int thr = (int)sqtmin[ti] + (int)sqtmin[tj] - Ts;  // prune: 2*max<=thr

        if (ti != curTi) {
            #pragma unroll
            for (int mt = 0; mt < 4; mt++) {
                const signed char* ar = q8 + (size_t)(iB + mt * 16 + lrow) * D + quad * 16;
                af[mt][0] = *(const intx4*)ar;
                af[mt][1] = *(const intx4*)(ar + 64);
            }
            curTi = ti;
        }

        int nti = ti, ntj = tj + 1;
        if (ntj == NT64) { ++nti; ntj = nti; }
        const bool more = (r + 1 < cnt);

        #pragma unroll
        for (int nt = 0; nt < 4; nt++) {
            intx4 acc[4] = {};
            #pragma unroll
            for (int kk = 0; kk < 2; kk++)
                #pragma unroll
                for (int mt = 0; mt < 4; mt++)
                    acc[mt] = __builtin_amdgcn_mfma_i32_16x16x64_i8(
                        af[mt][kk], bf[nt][kk], acc[mt], 0, 0, 0);

            if (more) {  // prefetch next pair's bf[nt]; never drained by a barrier
                const signed char* br =
                    q8 + (size_t)(ntj * T64 + nt * 16 + lrow) * D + quad * 16;
                bf[nt][0] = *(const intx4*)br;
                bf[nt][1] = *(const intx4*)(br + 64);
            }

            // ---- O(1)/elem screen: lane max of acc, one ballot ----
            int lm = acc[0][0];
            #pragma unroll
            for (int mt = 0; mt < 4; mt++)
                #pragma unroll
                for (int reg = 0; reg < 4; reg++)
                    lm = max(lm, acc[mt][reg]);

            if (__any(2 * lm > thr)) {
                // exact slow path (the 128 diagonal tiles; ~never off-diag)
                // C/D layout: col = lane&15, row = quad*4 + reg [learn_hip m89]
                const int sj = sqv[jB + nt * 16 + lrow];
                float colv = 0.f;
                #pragma unroll
                for (int mt = 0; mt < 4; mt++)
                    #pragma unroll
                    for (int reg = 0; reg < 4; reg++) {
                        int si = sqv[iB + mt * 16 + quad * 4 + reg];
                        int d2s = si + sj - (acc[mt][reg] << 1);
                        float p = __builtin_amdgcn_exp2f((float)d2s * c2);
                        colv += p;
                        float rv = p;
                        rv += __shfl_xor(rv, 1, 64);
                        rv += __shfl_xor(rv, 2, 64);
                        rv += __shfl_xor(rv, 4, 64);
                        rv += __shfl_xor(rv, 8, 64);
                        if (lrow == 0)
                            atomicAdd(&rowsum[iB + mt * 16 + quad * 4 + reg], rv);
                    }
                if (ti != tj) {  // symmetric column contribution
                    colv += __shfl_xor(colv, 16, 64);
                    colv += __shfl_xor(colv, 32, 64);
                    if (quad == 0)
                        atomicAdd(&rowsum[jB + nt * 16 + lrow], colv);
                }
            }
        }

        ti = nti; tj = ntj;
    }
}

// k3: IXT = (ln N - mean_i ln rowsum[i]) / ln 2
__global__ __launch_bounds__(1024) void k3_final(
        const float* __restrict__ rowsum, float* __restrict__ out_ixt) {
    __shared__ float red[16];
    int t = threadIdx.x;
    float local = 0.f;
    for (int i = t; i < N; i += 1024) local += logf(rowsum[i]);
    #pragma unroll
    for (int m = 1; m < 64; m <<= 1) local += __shfl_xor(local, m, 64);
    if ((t & 63) == 0) red[t >> 6] = local;
    __syncthreads();
    if (t < 16) {
        float v = red[t];
        #pragma unroll
        for (int m = 1; m < 16; m <<= 1) v += __shfl_xor(v, m, 64);
        if (t == 0) {
            float kde = v / (float)N;
            out_ixt[0] = (logf((float)N) - kde) * 1.4426950408889634f;
        }
    }
}

extern "C" void kernel_launch(void* const* d_in, const int* in_sizes, int n_in,
                              void* d_out, int out_size, void* d_ws, size_t ws_size,
                              hipStream_t stream) {
    const float* x     = (const float*)d_in[0];
    const float* phi   = (const float*)d_in[1];
    const float* noise = (const float*)d_in[2];
    float* out = (float*)d_out;

    float* rowsum = (float*)d_ws;                      // N floats
    int*   sqv    = (int*)(rowsum + N);                // N ints
    u32*   sqtmin = (u32*)(sqv + N);                   // NT64 u32 (poison = +inf)
    signed char* q8 = (signed char*)(sqtmin + NT64);   // N*D int8 = 1 MB

    k1_prep<<<(N * 16) / 256, 256, 0, stream>>>(x, phi, noise, out, q8, sqv,
                                                sqtmin, rowsum);
    k2_gram<<<1024, 256, 0, stream>>>(q8, phi, sqv, sqtmin, rowsum);
    k3_final<<<1, 1024, 0, stream>>>(rowsum, out + (size_t)N * D);
}